// Round 7
// baseline (94.235 us; speedup 1.0000x reference)
//
#include <hip/hip_runtime.h>

#define W_ 8192
#define NBATCH 2048
#define TB 2
#define NT 256
#define CCH 1024
#define NCH 8
#define SUBE 256
#define NSUB 32
#define RING 2048
#define RSTR 2052
#define IRW 1040

typedef unsigned short u16_t;
typedef _Float16 h2v __attribute__((ext_vector_type(2)));

__device__ __forceinline__ u16_t f2h(float x){ _Float16 h=(_Float16)x; return __builtin_bit_cast(u16_t,h); }
__device__ __forceinline__ float h2f(u16_t u){ return (float)__builtin_bit_cast(_Float16,u); }
__device__ __forceinline__ unsigned pk2(float a,float b){ return (unsigned)f2h(a)|((unsigned)f2h(b)<<16); }
__device__ __forceinline__ float dot2u(unsigned a,unsigned b,float c){
#if __has_builtin(__builtin_amdgcn_fdot2)
  return __builtin_amdgcn_fdot2(__builtin_bit_cast(h2v,a),__builtin_bit_cast(h2v,b),c,false);
#else
  h2v ha=__builtin_bit_cast(h2v,a), hb=__builtin_bit_cast(h2v,b);
  return c+(float)ha[0]*(float)hb[0]+(float)ha[1]*(float)hb[1];
#endif
}
__device__ __forceinline__ unsigned pkrtz(float a,float b){
#if __has_builtin(__builtin_amdgcn_cvt_pkrtz)
  return __builtin_bit_cast(unsigned, __builtin_amdgcn_cvt_pkrtz(a,b));
#else
  return pk2(a,b);
#endif
}
__device__ __forceinline__ float softplusf(float x){ return fmaxf(x,0.f)+log1pf(expf(-fabsf(x))); }

// SoA-of-pairs pack: Tp[q*W_+w] = f16pair q of element w.
__global__ void doas_pack(const float* __restrict__ absn, const float* __restrict__ cbn,
                          const float* __restrict__ ray, unsigned* __restrict__ Tp){
  int w = blockIdx.x*256 + threadIdx.x;
  if (w >= W_) return;
  #pragma unroll
  for (int q=0;q<4;++q) Tp[q*W_+w]     = pk2(absn[(2*q)*W_+w], absn[(2*q+1)*W_+w]);
  #pragma unroll
  for (int q=0;q<4;++q) Tp[(4+q)*W_+w] = pk2(cbn[(2*q)*W_+w],  cbn[(2*q+1)*W_+w]);
  Tp[8*W_+w] = pk2(cbn[8*W_+w], ray[w]);
}

template<int PACKED>
__global__ __launch_bounds__(NT, 4)
void doas_main(const float* __restrict__ gas, const int* __restrict__ iid,
               const float* __restrict__ nuis, const float* __restrict__ air,
               const float* __restrict__ wl, const float* __restrict__ absn,
               const float* __restrict__ cbn, const float* __restrict__ ray,
               const float* __restrict__ emb, const float* __restrict__ w1,
               const float* __restrict__ b1, const float* __restrict__ w2,
               const float* __restrict__ b2, const unsigned* __restrict__ Tp,
               float* __restrict__ out)
{
  extern __shared__ char smem[];
  float* ringF = (float*)smem;                               // [TB][RSTR] f32
  float* irowS = (float*)(smem + TB*RSTR*4);                 // [TB][IRW] f32
  float* hS    = (float*)(smem + TB*RSTR*4 + TB*IRW*4);      // [TB][64]
  float* pS    = hS + TB*64;                                 // [TB][8]
  float* scalS = pS + TB*8;                                  // [TB][32]
  float* wsumS = scalS + TB*32;                              // [NT/64]

  const int tid = threadIdx.x;
  const int r0 = blockIdx.x * TB;

  // ---------- setup: per-row MLP ----------
  if (tid < TB*64) {
    int rr = tid >> 6, j = tid & 63;
    int id = iid[r0 + rr];
    float acc = b1[j];
    const float* nrow = nuis + (size_t)(r0 + rr) * 8;
    #pragma unroll
    for (int i = 0; i < 8; ++i) acc = fmaf(nrow[i], w1[i*64 + j], acc);
    const float* erow = emb + (size_t)id * 128;
    for (int i = 0; i < 128; ++i) acc = fmaf(erow[i], w1[(8+i)*64 + j], acc);
    hS[rr*64 + j] = 0.5f * acc * (1.0f + erff(acc * 0.70710678118654752f));
  }
  __syncthreads();
  if (tid < TB*7) {
    int rr = tid / 7, k = tid % 7;
    float p = b2[k];
    for (int j = 0; j < 64; ++j) p = fmaf(hS[rr*64+j], w2[j*7+k], p);
    pS[rr*8+k] = p;
  }
  __syncthreads();
  if (tid < TB) {
    int rr = tid;
    float p0=pS[rr*8+0], p1=pS[rr*8+1], p2=pS[rr*8+2], p3=pS[rr*8+3],
          p4=pS[rr*8+4], p5=pS[rr*8+5], p6=pS[rr*8+6];
    float gainv = softplusf(p0) + 0.001f;
    float offv  = p1;
    float woffv = 0.05f * tanhf(p2);
    float wscv  = 1.0f + 0.005f * tanhf(p3);
    float lsf   = fminf(fmaxf(softplusf(p4) + 0.001f, 0.2f), 5.0f);
    float strv  = (1.0f/(1.0f+expf(-p5))) * 0.05f;
    float nlin  = 0.02f * tanhf(p6);
    nlin = fminf(fmaxf(nlin, -0.04f), 0.04f);
    strv = fminf(fmaxf(strv, 0.0f), 0.2f);
    float iw = 1.0f/(lsf + 1e-6f);
    float ks[15]; float ksum = 0.f;
    #pragma unroll
    for (int k2=0;k2<15;++k2){ float pp=(float)(k2-7)*iw; float e=expf(-0.5f*pp*pp); ks[k2]=e; ksum+=e; }
    float inv = 1.0f/ksum;
    float* sc = scalS + rr*32;
    #pragma unroll
    for (int k2=0;k2<15;++k2) sc[k2]=ks[k2]*inv;
    sc[15]=wscv; sc[16]=woffv; sc[17]=gainv; sc[18]=offv; sc[19]=nlin; sc[20]=strv;
    sc[22]=air[r0+rr];
    #pragma unroll
    for (int g=0; g<8; ++g) sc[23+g] = gas[(size_t)(r0+rr)*8+g];
  }
  __syncthreads();

  // ---------- block-uniform diff coefficients -> SGPRs ----------
  unsigned csg[TB][9];
  #pragma unroll
  for (int rr=0; rr<TB; ++rr){
    const float* scr = scalS + rr*32;
    float amr = scr[22];
    #pragma unroll
    for (int q=0;q<4;++q)
      csg[rr][q] = (unsigned)__builtin_amdgcn_readfirstlane(
          (int)pk2(scr[23+2*q]*amr, scr[23+2*q+1]*amr));
    #pragma unroll
    for (int q=0;q<4;++q)
      csg[rr][4+q] = (unsigned)__builtin_amdgcn_readfirstlane(
          (int)pk2(scr[23+2*q], scr[23+2*q+1]));
    csg[rr][8] = (unsigned)__builtin_amdgcn_readfirstlane((int)pk2(1.0f, amr));
  }

  // ---------- per-thread row state ----------
  const int r  = tid >> 7;   // 0..1
  const int wi = tid & 127;  // 0..127
  const float* sc = scalS + r*32;
  float kw[15];
  #pragma unroll
  for (int k2=0;k2<15;++k2) kw[k2]=sc[k2];
  const float wscale = sc[15], woff = sc[16], gainv = sc[17], offv = sc[18], nlin = sc[19];
  const float posoff = (300.0f*(wscale - 1.0f) + woff) * (8191.0f/100.0f);

  float* ring = ringF + r*RSTR;
  float* irow = irowS + r*IRW;

  // inline diff: one 256-element subchunk, both rows (loads -> dot2 -> LDS)
  auto do_diff = [&](int s){
    const int e = s*SUBE + tid;
    float a0=0.f, a1=0.f;
    if (PACKED){
      #pragma unroll
      for (int q=0;q<9;++q){
        unsigned d = Tp[q*W_ + e];
        a0 = dot2u(d, csg[0][q], a0);
        a1 = dot2u(d, csg[1][q], a1);
      }
    } else {
      float av[9][2];
      #pragma unroll
      for (int q=0;q<4;++q){ av[q][0]=absn[(2*q)*W_+e]; av[q][1]=absn[(2*q+1)*W_+e]; }
      #pragma unroll
      for (int q=0;q<4;++q){ av[4+q][0]=cbn[(2*q)*W_+e]; av[4+q][1]=cbn[(2*q+1)*W_+e]; }
      av[8][0]=cbn[8*W_+e]; av[8][1]=ray[e];
      float acc[TB]={0.f,0.f};
      #pragma unroll
      for (int rr=0;rr<TB;++rr){
        #pragma unroll
        for (int q=0;q<9;++q){
          acc[rr] = fmaf(h2f((u16_t)(csg[rr][q]&0xffffu)), av[q][0], acc[rr]);
          acc[rr] = fmaf(h2f((u16_t)(csg[rr][q]>>16)),     av[q][1], acc[rr]);
        }
      }
      a0=acc[0]; a1=acc[1];
    }
    const int p = e & (RING-1);
    ringF[p] = a0; ringF[RSTR + p] = a1;
    if (p == 0){ ringF[RING] = a0; ringF[RSTR + RING] = a1; }
  };

  // prologue: subs 0..4 cover elements 0..1279 (interp(0) needs <=1199)
  do_diff(0); do_diff(1); do_diff(2); do_diff(3); do_diff(4);

  float accsum = 0.f;
  unsigned nlp[NCH][4];

  #pragma unroll
  for (int c = 0; c < NCH; ++c) {
    const int cs = c * CCH;
    const bool eLo = (c == 0), eHi = (c == NCH-1);
    if (c >= 1) {
      #pragma unroll
      for (int ss = 1; ss <= 4; ++ss) {
        int s = 4*c + ss;
        if (s < NSUB) do_diff(s);
      }
    }
    __syncthreads();   // ring writes visible
    // ---- interp(c): irow[k] = warped diff at global index cs-7+k, k in [0,1038) ----
    #pragma unroll
    for (int it = 0; it < 5; ++it) {
      int jj = it*256 + 2*wi;
      if (jj < CCH + 14) {
        float v2[2];
        #pragma unroll
        for (int u=0; u<2; ++u){
          int j = cs - 7 + jj + u;
          int jc = j;
          if (eLo) jc = max(jc, 0);
          if (eHi) jc = min(jc, W_-1);
          float pos = fmaf((float)jc, wscale, posoff);
          if (eLo) pos = fmaxf(pos, 0.0f);
          if (eHi) pos = fminf(pos, 8191.0f);
          int i0 = (int)pos;
          if (eHi) i0 = min(i0, W_-2);
          float fr = pos - (float)i0;
          int p = i0 & (RING-1);
          float d0 = ring[p], d1 = ring[p+1];
          v2[u] = fmaf(fr, d1-d0, d0);
        }
        *(float2*)(irow + jj) = make_float2(v2[0], v2[1]);
      }
    }
    __syncthreads();   // irow ready
    // ---- conv(15) + exp + post + nl ; thread owns 8 consecutive outputs ----
    {
      const int b0 = 8*wi;
      const float4* qp = (const float4*)(irow + b0);
      float4 A=qp[0], B=qp[1], C=qp[2], D=qp[3], E=qp[4], F=qp[5];
      float wr[24] = {A.x,A.y,A.z,A.w, B.x,B.y,B.z,B.w, C.x,C.y,C.z,C.w,
                      D.x,D.y,D.z,D.w, E.x,E.y,E.z,E.w, F.x,F.y,F.z,F.w};
      float nlv[8];
      #pragma unroll
      for (int j=0;j<8;++j){
        float cv = 0.f;
        #pragma unroll
        for (int t=0;t<15;++t) cv = fmaf(wr[j+t], kw[t], cv);
        float counts = __expf(-cv);
        float post = fmaf(gainv, counts, offv);
        float v = fmaf(nlin*post, post, post);
        accsum += v;
        nlv[j] = v;
      }
      nlp[c][0] = pkrtz(nlv[0], nlv[1]);
      nlp[c][1] = pkrtz(nlv[2], nlv[3]);
      nlp[c][2] = pkrtz(nlv[4], nlv[5]);
      nlp[c][3] = pkrtz(nlv[6], nlv[7]);
    }
  }

  // ---------- row mean ----------
  float s = accsum;
  #pragma unroll
  for (int off2 = 32; off2 >= 1; off2 >>= 1) s += __shfl_down(s, off2);
  if ((tid & 63) == 0) wsumS[tid >> 6] = s;
  __syncthreads();
  if (tid < TB) scalS[tid*32 + 21] = (wsumS[2*tid] + wsumS[2*tid+1]) * (1.0f/8192.0f);
  __syncthreads();

  // ---------- final write ----------
  {
    const float strv = sc[20];
    const float meanv = sc[21];
    const float aa = 1.0f - strv;
    const float bb = strv * meanv;
    float* orow = out + (size_t)(r0 + r) * W_;
    #pragma unroll
    for (int c = 0; c < NCH; ++c) {
      unsigned u0 = nlp[c][0], u1 = nlp[c][1], u2 = nlp[c][2], u3 = nlp[c][3];
      float4 o0, o1;
      o0.x = fmaf(aa, h2f((u16_t)(u0 & 0xffffu)), bb);
      o0.y = fmaf(aa, h2f((u16_t)(u0 >> 16)),     bb);
      o0.z = fmaf(aa, h2f((u16_t)(u1 & 0xffffu)), bb);
      o0.w = fmaf(aa, h2f((u16_t)(u1 >> 16)),     bb);
      o1.x = fmaf(aa, h2f((u16_t)(u2 & 0xffffu)), bb);
      o1.y = fmaf(aa, h2f((u16_t)(u2 >> 16)),     bb);
      o1.z = fmaf(aa, h2f((u16_t)(u3 & 0xffffu)), bb);
      o1.w = fmaf(aa, h2f((u16_t)(u3 >> 16)),     bb);
      float* dst = orow + c*CCH + 8*wi;
      *(float4*)(dst)     = o0;
      *(float4*)(dst + 4) = o1;
    }
  }
}

extern "C" void kernel_launch(void* const* d_in, const int* in_sizes, int n_in,
                              void* d_out, int out_size, void* d_ws, size_t ws_size,
                              hipStream_t stream) {
  const float* gas  = (const float*)d_in[0];
  const int*   iid  = (const int*)d_in[1];
  const float* nuis = (const float*)d_in[2];
  const float* air  = (const float*)d_in[3];
  const float* wl   = (const float*)d_in[4];
  const float* absn = (const float*)d_in[5];
  const float* cbn  = (const float*)d_in[6];
  const float* ray  = (const float*)d_in[7];
  const float* emb  = (const float*)d_in[8];
  const float* w1   = (const float*)d_in[9];
  const float* b1   = (const float*)d_in[10];
  const float* w2   = (const float*)d_in[11];
  const float* b2   = (const float*)d_in[12];
  float* out = (float*)d_out;
  (void)in_sizes; (void)n_in; (void)out_size; (void)wl;

  const size_t ldsBytes = (size_t)TB*RSTR*4 + (size_t)TB*IRW*4
                        + (size_t)TB*64*4 + (size_t)TB*8*4 + (size_t)TB*32*4 + (NT/64)*4;
  const size_t packBytes = (size_t)9 * W_ * 4;

  if (ws_size >= packBytes) {
    unsigned* Tp = (unsigned*)d_ws;
    hipLaunchKernelGGL(doas_pack, dim3(W_/256), dim3(256), 0, stream, absn, cbn, ray, Tp);
    hipFuncSetAttribute(reinterpret_cast<const void*>(&doas_main<1>),
                        hipFuncAttributeMaxDynamicSharedMemorySize, (int)ldsBytes);
    hipLaunchKernelGGL((doas_main<1>), dim3(NBATCH/TB), dim3(NT), ldsBytes, stream,
                       gas, iid, nuis, air, wl, absn, cbn, ray, emb, w1, b1, w2, b2, Tp, out);
  } else {
    hipFuncSetAttribute(reinterpret_cast<const void*>(&doas_main<0>),
                        hipFuncAttributeMaxDynamicSharedMemorySize, (int)ldsBytes);
    hipLaunchKernelGGL((doas_main<0>), dim3(NBATCH/TB), dim3(NT), ldsBytes, stream,
                       gas, iid, nuis, air, wl, absn, cbn, ray, emb, w1, b1, w2, b2,
                       (const unsigned*)nullptr, out);
  }
}

// Round 8
// 68.394 us; speedup vs baseline: 1.3778x; 1.3778x over previous
//
#include <hip/hip_runtime.h>

#define W_ 8192
#define NBATCH 2048
#define NT 256
#define WPB 4
#define SEG 2048
#define RING 2048
#define IRW 544     // f16 units per wave irow (528 used)
#define NCHW 4      // 512-output chunks per wave

typedef unsigned short u16_t;
typedef _Float16 h2v __attribute__((ext_vector_type(2)));

__device__ __forceinline__ u16_t f2h(float x){ _Float16 h=(_Float16)x; return __builtin_bit_cast(u16_t,h); }
__device__ __forceinline__ float h2f(u16_t u){ return (float)__builtin_bit_cast(_Float16,u); }
__device__ __forceinline__ unsigned pk2(float a,float b){ return (unsigned)f2h(a)|((unsigned)f2h(b)<<16); }
__device__ __forceinline__ float dot2u(unsigned a,unsigned b,float c){
#if __has_builtin(__builtin_amdgcn_fdot2)
  return __builtin_amdgcn_fdot2(__builtin_bit_cast(h2v,a),__builtin_bit_cast(h2v,b),c,false);
#else
  h2v ha=__builtin_bit_cast(h2v,a), hb=__builtin_bit_cast(h2v,b);
  return c+(float)ha[0]*(float)hb[0]+(float)ha[1]*(float)hb[1];
#endif
}
__device__ __forceinline__ unsigned pkrtz(float a,float b){
#if __has_builtin(__builtin_amdgcn_cvt_pkrtz)
  return __builtin_bit_cast(unsigned, __builtin_amdgcn_cvt_pkrtz(a,b));
#else
  return pk2(a,b);
#endif
}
__device__ __forceinline__ unsigned alignb(unsigned hi, unsigned lo){
#if __has_builtin(__builtin_amdgcn_alignbit)
  return __builtin_amdgcn_alignbit(hi, lo, 16);
#else
  return (lo >> 16) | (hi << 16);
#endif
}
__device__ __forceinline__ float softplusf(float x){ return fmaxf(x,0.f)+log1pf(expf(-fabsf(x))); }
__device__ __forceinline__ float rflf(const float* p){
  return __builtin_bit_cast(float, __builtin_amdgcn_readfirstlane(__builtin_bit_cast(int, *p)));
}
__device__ __forceinline__ unsigned rflu(const unsigned* p){
  return (unsigned)__builtin_amdgcn_readfirstlane((int)*p);
}
__device__ __forceinline__ unsigned rflv(unsigned v){
  return (unsigned)__builtin_amdgcn_readfirstlane((int)v);
}

// SoA-of-pairs pack: Tp[q*W_+w] = f16pair q of element w.
__global__ void doas_pack(const float* __restrict__ absn, const float* __restrict__ cbn,
                          const float* __restrict__ ray, unsigned* __restrict__ Tp){
  int w = blockIdx.x*256 + threadIdx.x;
  if (w >= W_) return;
  #pragma unroll
  for (int q=0;q<4;++q) Tp[q*W_+w]     = pk2(absn[(2*q)*W_+w], absn[(2*q+1)*W_+w]);
  #pragma unroll
  for (int q=0;q<4;++q) Tp[(4+q)*W_+w] = pk2(cbn[(2*q)*W_+w],  cbn[(2*q+1)*W_+w]);
  Tp[8*W_+w] = pk2(cbn[8*W_+w], ray[w]);
}

// Kernel A: diffG[row][w] (f16) for all rows. Block: 4 rows x 512 elements.
__global__ __launch_bounds__(256, 2)
void doas_diff(const unsigned* __restrict__ Tp, const float* __restrict__ gas,
               const float* __restrict__ air, u16_t* __restrict__ diffG){
  const int tid = threadIdx.x;
  const int e0 = blockIdx.x*512 + 2*tid;
  const int r0 = blockIdx.y*4;
  unsigned csgA[4][9];
  #pragma unroll
  for (int rr=0;rr<4;++rr){
    const float am = air[r0+rr];
    const float* gfp = gas + (size_t)(r0+rr)*8;
    #pragma unroll
    for (int q=0;q<4;++q) csgA[rr][q]   = rflv(pk2(gfp[2*q]*am, gfp[2*q+1]*am));
    #pragma unroll
    for (int q=0;q<4;++q) csgA[rr][4+q] = rflv(pk2(gfp[2*q],    gfp[2*q+1]));
    csgA[rr][8] = rflv(pk2(1.0f, am));
  }
  uint2 dq[9];
  #pragma unroll
  for (int q=0;q<9;++q) dq[q] = *(const uint2*)(Tp + q*W_ + e0);
  #pragma unroll
  for (int rr=0;rr<4;++rr){
    float a0=0.f, a1=0.f;
    #pragma unroll
    for (int q=0;q<9;++q){
      a0 = dot2u(dq[q].x, csgA[rr][q], a0);
      a1 = dot2u(dq[q].y, csgA[rr][q], a1);
    }
    ((unsigned*)diffG)[((size_t)(r0+rr)*W_ + e0)>>1] = pkrtz(a0, a1);
  }
}

// Kernel B: one row per block; wave wid owns segment [2048*wid, +2048).
__global__ __launch_bounds__(NT, 2)
void doas_mainB(const float* __restrict__ gas, const int* __restrict__ iid,
                const float* __restrict__ nuis, const float* __restrict__ air,
                const float* __restrict__ emb, const float* __restrict__ w1,
                const float* __restrict__ b1, const float* __restrict__ w2,
                const float* __restrict__ b2, const u16_t* __restrict__ diffW,
                float* __restrict__ out)
{
  __shared__ u16_t irowS[WPB][IRW];
  __shared__ float hS[64];
  __shared__ float pS[8];
  __shared__ float scalS[44];
  __shared__ float wsumS[WPB];

  const int tid = threadIdx.x;
  const int row = blockIdx.x;

  // ---------- per-row MLP ----------
  if (tid < 64) {
    const int j = tid;
    const int id = iid[row];
    float acc = b1[j];
    const float* nrow = nuis + (size_t)row * 8;
    #pragma unroll
    for (int i = 0; i < 8; ++i) acc = fmaf(nrow[i], w1[i*64 + j], acc);
    const float* erow = emb + (size_t)id * 128;
    for (int i = 0; i < 128; ++i) acc = fmaf(erow[i], w1[(8+i)*64 + j], acc);
    hS[j] = 0.5f * acc * (1.0f + erff(acc * 0.70710678118654752f));
  }
  __syncthreads();
  if (tid < 7) {
    float p = b2[tid];
    for (int j = 0; j < 64; ++j) p = fmaf(hS[j], w2[j*7+tid], p);
    pS[tid] = p;
  }
  __syncthreads();
  if (tid == 0) {
    float p0=pS[0], p1=pS[1], p2=pS[2], p3=pS[3], p4=pS[4], p5=pS[5], p6=pS[6];
    float gainv = softplusf(p0) + 0.001f;
    float offv  = p1;
    float woffv = 0.05f * tanhf(p2);
    float wscv  = 1.0f + 0.005f * tanhf(p3);
    float lsf   = fminf(fmaxf(softplusf(p4) + 0.001f, 0.2f), 5.0f);
    float strv  = fminf(fmaxf((1.0f/(1.0f+expf(-p5))) * 0.05f, 0.0f), 0.2f);
    float nlin  = fminf(fmaxf(0.02f * tanhf(p6), -0.04f), 0.04f);
    float iw = 1.0f/(lsf + 1e-6f);
    float ks[15]; float ksum = 0.f;
    #pragma unroll
    for (int k2=0;k2<15;++k2){ float pp=(float)(k2-7)*iw; float e=expf(-0.5f*pp*pp); ks[k2]=e; ksum+=e; }
    float inv = 1.0f/ksum;
    scalS[15] = wscv;
    scalS[16] = (300.0f*(wscv - 1.0f) + woffv) * (8191.0f/100.0f);  // posoff
    scalS[17] = gainv; scalS[18] = offv; scalS[19] = nlin; scalS[20] = strv;
    unsigned* su = (unsigned*)scalS;
    #pragma unroll
    for (int i=0;i<7;++i) su[32+i] = pk2(ks[2*i]*inv, ks[2*i+1]*inv);
    su[39] = pk2(ks[14]*inv, 0.0f);   // k14lo
    su[40] = pk2(0.0f, ks[14]*inv);   // k14hi
  }
  __syncthreads();

  // ---------- wave-uniform state -> SGPRs ----------
  const int wid = tid >> 6, l = tid & 63;
  const int segbase = wid * SEG;
  const unsigned* scalU = (const unsigned*)scalS;
  unsigned kwp[7];
  #pragma unroll
  for (int i=0;i<7;++i) kwp[i] = rflu(scalU + 32 + i);
  const unsigned k14lo = rflu(scalU + 39), k14hi = rflu(scalU + 40);
  const float wscale = rflf(scalS + 15), posoff = rflf(scalS + 16);
  const float gainv  = rflf(scalS + 17), offv   = rflf(scalS + 18);
  const float nlin   = rflf(scalS + 19), strv   = rflf(scalS + 20);

  u16_t* irow = &irowS[wid][0];
  unsigned* irowU = (unsigned*)irow;
  const u16_t* dG = diffW + (size_t)row * W_;

  float accsum = 0.f;
  unsigned nlp[NCHW][4];

  #pragma unroll
  for (int c = 0; c < NCHW; ++c) {
    // ---- interp: irow[k] (k=0..527) = warped diff at j = segbase+512c-8+k ----
    {
      const int cbase = segbase + (c << 9) - 8;
      #pragma unroll
      for (int it = 0; it < 5; ++it) {
        const int pi = it*64 + l;
        if (pi < 264) {
          float v2[2];
          #pragma unroll
          for (int u=0; u<2; ++u){
            const int j = cbase + 2*pi + u;
            const int jc = min(max(j, 0), W_-1);
            float pos = fmaf((float)jc, wscale, posoff);
            pos = fminf(fmaxf(pos, 0.0f), 8191.0f);
            const int i0 = min((int)pos, W_-2);
            const float fr = pos - (float)i0;
            const float d0 = h2f(dG[i0]);
            const float d1 = h2f(dG[i0+1]);
            v2[u] = fmaf(fr, d1-d0, d0);
          }
          irowU[pi] = pkrtz(v2[0], v2[1]);
        }
      }
    }
    __builtin_amdgcn_wave_barrier();
    // ---- conv(15) + exp + post + nl ; lane owns 8 outputs at segbase+512c+8l ----
    {
      const uint4* qp = (const uint4*)irow + l;
      const uint4 A = qp[0], B = qp[1], C = qp[2];
      unsigned q[12] = {A.x,A.y,A.z,A.w, B.x,B.y,B.z,B.w, C.x,C.y,C.z,C.w};
      unsigned sh[10];
      #pragma unroll
      for (int m=0;m<10;++m) sh[m] = alignb(q[m+1], q[m]);
      float nlv[8];
      #pragma unroll
      for (int t=0;t<8;++t){
        const int s2 = t >> 1;
        float cv = 0.f;
        if ((t & 1) == 0){
          #pragma unroll
          for (int i=0;i<7;++i) cv = dot2u(sh[s2+i], kwp[i], cv);
          cv = dot2u(q[s2+7], k14hi, cv);
        } else {
          #pragma unroll
          for (int i=0;i<7;++i) cv = dot2u(q[s2+1+i], kwp[i], cv);
          cv = dot2u(q[s2+8], k14lo, cv);
        }
        const float counts = __expf(-cv);
        const float post = fmaf(gainv, counts, offv);
        const float v = fmaf(nlin*post, post, post);
        accsum += v;
        nlv[t] = v;
      }
      nlp[c][0] = pkrtz(nlv[0], nlv[1]);
      nlp[c][1] = pkrtz(nlv[2], nlv[3]);
      nlp[c][2] = pkrtz(nlv[4], nlv[5]);
      nlp[c][3] = pkrtz(nlv[6], nlv[7]);
    }
    __builtin_amdgcn_wave_barrier();
  }

  // ---------- row mean ----------
  float s = accsum;
  #pragma unroll
  for (int off2 = 32; off2 >= 1; off2 >>= 1) s += __shfl_down(s, off2);
  if (l == 0) wsumS[wid] = s;
  __syncthreads();
  const float meanv = (wsumS[0]+wsumS[1]+wsumS[2]+wsumS[3]) * (1.0f/8192.0f);

  // ---------- final write ----------
  {
    const float aa = 1.0f - strv;
    const float bb = strv * meanv;
    float* orow = out + (size_t)row * W_;
    #pragma unroll
    for (int c = 0; c < NCHW; ++c) {
      const unsigned u0 = nlp[c][0], u1 = nlp[c][1], u2 = nlp[c][2], u3 = nlp[c][3];
      float4 o0, o1;
      o0.x = fmaf(aa, h2f((u16_t)(u0 & 0xffffu)), bb);
      o0.y = fmaf(aa, h2f((u16_t)(u0 >> 16)),     bb);
      o0.z = fmaf(aa, h2f((u16_t)(u1 & 0xffffu)), bb);
      o0.w = fmaf(aa, h2f((u16_t)(u1 >> 16)),     bb);
      o1.x = fmaf(aa, h2f((u16_t)(u2 & 0xffffu)), bb);
      o1.y = fmaf(aa, h2f((u16_t)(u2 >> 16)),     bb);
      o1.z = fmaf(aa, h2f((u16_t)(u3 & 0xffffu)), bb);
      o1.w = fmaf(aa, h2f((u16_t)(u3 >> 16)),     bb);
      float* dst = orow + segbase + (c << 9) + 8*l;
      *(float4*)(dst)     = o0;
      *(float4*)(dst + 4) = o1;
    }
  }
}

// ---------------- fallback: R6 monolithic kernel (tested at 76 us) ----------------
template<int PACKED>
__global__ __launch_bounds__(NT, 2)
void doas_mono(const float* __restrict__ gas, const int* __restrict__ iid,
               const float* __restrict__ nuis, const float* __restrict__ air,
               const float* __restrict__ wl, const float* __restrict__ absn,
               const float* __restrict__ cbn, const float* __restrict__ ray,
               const float* __restrict__ emb, const float* __restrict__ w1,
               const float* __restrict__ b1, const float* __restrict__ w2,
               const float* __restrict__ b2, const unsigned* __restrict__ Tp,
               float* __restrict__ out)
{
  __shared__ u16_t ringS[WPB][RING];
  __shared__ u16_t irowS[WPB][IRW];
  __shared__ float hS[64];
  __shared__ float pS[8];
  __shared__ float scalS[52];
  __shared__ float wsumS[WPB];

  const int tid = threadIdx.x;
  const int row = blockIdx.x;

  if (tid < 64) {
    const int j = tid;
    const int id = iid[row];
    float acc = b1[j];
    const float* nrow = nuis + (size_t)row * 8;
    #pragma unroll
    for (int i = 0; i < 8; ++i) acc = fmaf(nrow[i], w1[i*64 + j], acc);
    const float* erow = emb + (size_t)id * 128;
    for (int i = 0; i < 128; ++i) acc = fmaf(erow[i], w1[(8+i)*64 + j], acc);
    hS[j] = 0.5f * acc * (1.0f + erff(acc * 0.70710678118654752f));
  }
  __syncthreads();
  if (tid < 7) {
    float p = b2[tid];
    for (int j = 0; j < 64; ++j) p = fmaf(hS[j], w2[j*7+tid], p);
    pS[tid] = p;
  }
  __syncthreads();
  if (tid == 0) {
    float p0=pS[0], p1=pS[1], p2=pS[2], p3=pS[3], p4=pS[4], p5=pS[5], p6=pS[6];
    float gainv = softplusf(p0) + 0.001f;
    float offv  = p1;
    float woffv = 0.05f * tanhf(p2);
    float wscv  = 1.0f + 0.005f * tanhf(p3);
    float lsf   = fminf(fmaxf(softplusf(p4) + 0.001f, 0.2f), 5.0f);
    float strv  = fminf(fmaxf((1.0f/(1.0f+expf(-p5))) * 0.05f, 0.0f), 0.2f);
    float nlin  = fminf(fmaxf(0.02f * tanhf(p6), -0.04f), 0.04f);
    float iw = 1.0f/(lsf + 1e-6f);
    float ks[15]; float ksum = 0.f;
    #pragma unroll
    for (int k2=0;k2<15;++k2){ float pp=(float)(k2-7)*iw; float e=expf(-0.5f*pp*pp); ks[k2]=e; ksum+=e; }
    float inv = 1.0f/ksum;
    scalS[15] = wscv;
    scalS[16] = (300.0f*(wscv - 1.0f) + woffv) * (8191.0f/100.0f);
    scalS[17] = gainv; scalS[18] = offv; scalS[19] = nlin; scalS[20] = strv;
    const float am = air[row];
    scalS[22] = am;
    unsigned* su = (unsigned*)scalS;
    #pragma unroll
    for (int i=0;i<7;++i) su[32+i] = pk2(ks[2*i]*inv, ks[2*i+1]*inv);
    su[39] = pk2(ks[14]*inv, 0.0f);
    su[40] = pk2(0.0f, ks[14]*inv);
    float gf[8];
    #pragma unroll
    for (int g=0; g<8; ++g){ gf[g] = gas[(size_t)row*8+g]; scalS[23+g] = gf[g]; }
    #pragma unroll
    for (int q=0;q<4;++q) su[41+q]   = pk2(gf[2*q]*am, gf[2*q+1]*am);
    #pragma unroll
    for (int q=0;q<4;++q) su[41+4+q] = pk2(gf[2*q],    gf[2*q+1]);
    su[49] = pk2(1.0f, am);
  }
  __syncthreads();

  const int wid = tid >> 6, l = tid & 63;
  const int segbase = wid * SEG;
  const unsigned* scalU = (const unsigned*)scalS;
  unsigned csg[9], kwp[7];
  #pragma unroll
  for (int q=0;q<9;++q) csg[q] = rflu(scalU + 41 + q);
  #pragma unroll
  for (int i=0;i<7;++i) kwp[i] = rflu(scalU + 32 + i);
  const unsigned k14lo = rflu(scalU + 39), k14hi = rflu(scalU + 40);
  const float wscale = rflf(scalS + 15), posoff = rflf(scalS + 16);
  const float gainv  = rflf(scalS + 17), offv   = rflf(scalS + 18);
  const float nlin   = rflf(scalS + 19), strv   = rflf(scalS + 20);

  u16_t* ring = &ringS[wid][0];
  unsigned* ringU = (unsigned*)ring;
  u16_t* irow = &irowS[wid][0];
  unsigned* irowU = (unsigned*)irow;

  auto do_diff = [&](int s){
    const int sbase = segbase - 256 + (s << 9);
    #pragma unroll
    for (int it=0; it<4; ++it){
      const int e0 = sbase + ((it*64 + l) << 1);
      const int eL = min(max(e0, 0), W_-2);
      float a0=0.f, a1=0.f;
      if (PACKED){
        #pragma unroll
        for (int q=0;q<9;++q){
          uint2 d = *(const uint2*)(Tp + q*W_ + eL);
          a0 = dot2u(d.x, csg[q], a0);
          a1 = dot2u(d.y, csg[q], a1);
        }
      } else {
        const float am = scalS[22];
        #pragma unroll
        for (int g=0; g<8; ++g){
          const float cg = scalS[23+g];
          const float ca = cg*am;
          a0 = fmaf(ca, absn[g*W_+eL],   a0); a0 = fmaf(cg, cbn[g*W_+eL],   a0);
          a1 = fmaf(ca, absn[g*W_+eL+1], a1); a1 = fmaf(cg, cbn[g*W_+eL+1], a1);
        }
        a0 += cbn[8*W_+eL]   + am*ray[eL];
        a1 += cbn[8*W_+eL+1] + am*ray[eL+1];
      }
      ringU[((unsigned)e0 & (RING-1)) >> 1] = pkrtz(a0, a1);
    }
  };

  float accsum = 0.f;
  unsigned nlp[NCHW][4];

  do_diff(0); do_diff(1);
  __builtin_amdgcn_wave_barrier();

  #pragma unroll
  for (int c = 0; c < NCHW; ++c) {
    if (c < 3) do_diff(c+2);
    __builtin_amdgcn_wave_barrier();
    {
      const int cbase = segbase + (c << 9) - 8;
      #pragma unroll
      for (int it = 0; it < 5; ++it) {
        const int pi = it*64 + l;
        if (pi < 264) {
          float v2[2];
          #pragma unroll
          for (int u=0; u<2; ++u){
            const int j = cbase + 2*pi + u;
            const int jc = min(max(j, 0), W_-1);
            float pos = fmaf((float)jc, wscale, posoff);
            pos = fminf(fmaxf(pos, 0.0f), 8191.0f);
            const int i0 = min((int)pos, W_-2);
            const float fr = pos - (float)i0;
            const float d0 = h2f(ring[ i0    & (RING-1)]);
            const float d1 = h2f(ring[(i0+1) & (RING-1)]);
            v2[u] = fmaf(fr, d1-d0, d0);
          }
          irowU[pi] = pkrtz(v2[0], v2[1]);
        }
      }
    }
    __builtin_amdgcn_wave_barrier();
    {
      const uint4* qp = (const uint4*)irow + l;
      const uint4 A = qp[0], B = qp[1], C = qp[2];
      unsigned q[12] = {A.x,A.y,A.z,A.w, B.x,B.y,B.z,B.w, C.x,C.y,C.z,C.w};
      unsigned sh[10];
      #pragma unroll
      for (int m=0;m<10;++m) sh[m] = alignb(q[m+1], q[m]);
      float nlv[8];
      #pragma unroll
      for (int t=0;t<8;++t){
        const int s2 = t >> 1;
        float cv = 0.f;
        if ((t & 1) == 0){
          #pragma unroll
          for (int i=0;i<7;++i) cv = dot2u(sh[s2+i], kwp[i], cv);
          cv = dot2u(q[s2+7], k14hi, cv);
        } else {
          #pragma unroll
          for (int i=0;i<7;++i) cv = dot2u(q[s2+1+i], kwp[i], cv);
          cv = dot2u(q[s2+8], k14lo, cv);
        }
        const float counts = __expf(-cv);
        const float post = fmaf(gainv, counts, offv);
        const float v = fmaf(nlin*post, post, post);
        accsum += v;
        nlv[t] = v;
      }
      nlp[c][0] = pkrtz(nlv[0], nlv[1]);
      nlp[c][1] = pkrtz(nlv[2], nlv[3]);
      nlp[c][2] = pkrtz(nlv[4], nlv[5]);
      nlp[c][3] = pkrtz(nlv[6], nlv[7]);
    }
    __builtin_amdgcn_wave_barrier();
  }

  float s = accsum;
  #pragma unroll
  for (int off2 = 32; off2 >= 1; off2 >>= 1) s += __shfl_down(s, off2);
  if (l == 0) wsumS[wid] = s;
  __syncthreads();
  const float meanv = (wsumS[0]+wsumS[1]+wsumS[2]+wsumS[3]) * (1.0f/8192.0f);

  {
    const float aa = 1.0f - strv;
    const float bb = strv * meanv;
    float* orow = out + (size_t)row * W_;
    #pragma unroll
    for (int c = 0; c < NCHW; ++c) {
      const unsigned u0 = nlp[c][0], u1 = nlp[c][1], u2 = nlp[c][2], u3 = nlp[c][3];
      float4 o0, o1;
      o0.x = fmaf(aa, h2f((u16_t)(u0 & 0xffffu)), bb);
      o0.y = fmaf(aa, h2f((u16_t)(u0 >> 16)),     bb);
      o0.z = fmaf(aa, h2f((u16_t)(u1 & 0xffffu)), bb);
      o0.w = fmaf(aa, h2f((u16_t)(u1 >> 16)),     bb);
      o1.x = fmaf(aa, h2f((u16_t)(u2 & 0xffffu)), bb);
      o1.y = fmaf(aa, h2f((u16_t)(u2 >> 16)),     bb);
      o1.z = fmaf(aa, h2f((u16_t)(u3 & 0xffffu)), bb);
      o1.w = fmaf(aa, h2f((u16_t)(u3 >> 16)),     bb);
      float* dst = orow + segbase + (c << 9) + 8*l;
      *(float4*)(dst)     = o0;
      *(float4*)(dst + 4) = o1;
    }
  }
}

extern "C" void kernel_launch(void* const* d_in, const int* in_sizes, int n_in,
                              void* d_out, int out_size, void* d_ws, size_t ws_size,
                              hipStream_t stream) {
  const float* gas  = (const float*)d_in[0];
  const int*   iid  = (const int*)d_in[1];
  const float* nuis = (const float*)d_in[2];
  const float* air  = (const float*)d_in[3];
  const float* wl   = (const float*)d_in[4];
  const float* absn = (const float*)d_in[5];
  const float* cbn  = (const float*)d_in[6];
  const float* ray  = (const float*)d_in[7];
  const float* emb  = (const float*)d_in[8];
  const float* w1   = (const float*)d_in[9];
  const float* b1   = (const float*)d_in[10];
  const float* w2   = (const float*)d_in[11];
  const float* b2   = (const float*)d_in[12];
  float* out = (float*)d_out;
  (void)in_sizes; (void)n_in; (void)out_size; (void)wl;

  const size_t packBytes = (size_t)9 * W_ * 4;
  const size_t diffBytes = (size_t)NBATCH * W_ * 2;

  if (ws_size >= packBytes + diffBytes) {
    unsigned* Tp = (unsigned*)d_ws;
    u16_t* diffG = (u16_t*)((char*)d_ws + packBytes);
    hipLaunchKernelGGL(doas_pack, dim3(W_/256), dim3(256), 0, stream, absn, cbn, ray, Tp);
    hipLaunchKernelGGL(doas_diff, dim3(W_/512, NBATCH/4), dim3(256), 0, stream,
                       Tp, gas, air, diffG);
    hipLaunchKernelGGL(doas_mainB, dim3(NBATCH), dim3(NT), 0, stream,
                       gas, iid, nuis, air, emb, w1, b1, w2, b2, diffG, out);
  } else if (ws_size >= packBytes) {
    unsigned* Tp = (unsigned*)d_ws;
    hipLaunchKernelGGL(doas_pack, dim3(W_/256), dim3(256), 0, stream, absn, cbn, ray, Tp);
    hipLaunchKernelGGL((doas_mono<1>), dim3(NBATCH), dim3(NT), 0, stream,
                       gas, iid, nuis, air, wl, absn, cbn, ray, emb, w1, b1, w2, b2, Tp, out);
  } else {
    hipLaunchKernelGGL((doas_mono<0>), dim3(NBATCH), dim3(NT), 0, stream,
                       gas, iid, nuis, air, wl, absn, cbn, ray, emb, w1, b1, w2, b2,
                       (const unsigned*)nullptr, out);
  }
}